// Round 4
// baseline (173.443 us; speedup 1.0000x reference)
//
#include <hip/hip_runtime.h>

#define DD 128         // EMBED_DIM
#define OVF_MAX 4096   // overflow list capacity (int4 entries)
#define EPB 12800      // edges per scatter chunk (runs ~16 edges = 131 B)
#define BSH 6          // bucket = row >> 6 (64 rows/bucket)
#define NB2 800        // max buckets (ceil(50000/64)=782)
#define BC2 1408       // bucket capacity: lambda=1024, +12 sigma
#define WTS 136

typedef __attribute__((ext_vector_type(8))) short short8;           // 8 bf16
typedef __attribute__((ext_vector_type(8))) unsigned short u16x8;   // 8 bf16
typedef __attribute__((ext_vector_type(4))) float f32x4;            // MFMA C/D

static __device__ __forceinline__ unsigned pack_bf16_2(float lo, float hi) {
  return __builtin_amdgcn_perm(__float_as_uint(hi) + 0x8000u,
                               __float_as_uint(lo) + 0x8000u, 0x07060302u);
}
static __device__ __forceinline__ unsigned short f2bf(float f) {
  return (unsigned short)((__float_as_uint(f) + 0x8000u) >> 16);
}
static __device__ __forceinline__ float bf2f(unsigned short h) {
  return __uint_as_float((unsigned)h << 16);
}

// ---------------------------------------------------------------------------
// Kernel A: blocks [0,nchunks) bucket-scatter edges into 64-row buckets.
// EPB=12800 -> per-(chunk,bucket) runs ~16 edges (131 B) -> line-sized
// single-owner writebacks (round-0 lesson restored at 64-row granularity).
// rows/cols/vals are read twice; second pass is L2-hot. Blocks [nchunks,..)
// MFMA GEMM with per-block W-transpose in LDS (independent of scatter).
// ---------------------------------------------------------------------------
__global__ __launch_bounds__(256) void kA_scatter_gemm(
    const float* __restrict__ U, const float* __restrict__ W,
    const int* __restrict__ rows, const int* __restrict__ cols,
    const float* __restrict__ vals, int* __restrict__ binctr,
    int2* __restrict__ bucket, int* __restrict__ ovf_cnt,
    int4* __restrict__ ovf, unsigned short* __restrict__ wb,
    int N, int E, int nchunks, int nbkt) {
  __shared__ union {
    struct {
      int hist[NB2];   // 3.2 KB
      int gbase[NB2];
      int lcur[NB2];
    } p1;              // 9.6 KB
    unsigned short Wt[DD][WTS];  // 34.8 KB
  } sm;
  const int t = threadIdx.x;

  if ((int)blockIdx.x < nchunks) {
    // ---- bucket scatter for one EPB-edge chunk ----
    const int c0 = blockIdx.x * EPB;
    const int n = min(EPB, E - c0);

    for (int j = t; j < nbkt; j += 256) { sm.p1.hist[j] = 0; sm.p1.lcur[j] = 0; }
    __syncthreads();

    // Pass A: histogram by bucket (rows read coalesced).
    for (int i = t; i < n; i += 256)
      atomicAdd(&sm.p1.hist[rows[c0 + i] >> BSH], 1);
    __syncthreads();

    // Reserve contiguous runs in each bucket.
    for (int j = t; j < nbkt; j += 256)
      if (sm.p1.hist[j] > 0)
        sm.p1.gbase[j] = atomicAdd(&binctr[j], sm.p1.hist[j]);
    __syncthreads();

    // Pass B: place edges into runs (rows/cols/vals re-read, L2-hot).
    for (int i = t; i < n; i += 256) {
      const int r = rows[c0 + i];
      const int b = r >> BSH;
      const int lpos = atomicAdd(&sm.p1.lcur[b], 1);
      const int idx = sm.p1.gbase[b] + lpos;
      const int col = cols[c0 + i];
      const float v = vals[c0 + i];
      if (idx < BC2) {
        // pack: bits[27:22] = row&63, bits[21:0] = col (col < 4M)
        bucket[(size_t)b * BC2 + idx] =
            make_int2(((r & 63) << 22) | col, __float_as_int(v));
      } else {
        const int o = atomicAdd(ovf_cnt, 1);
        if (o < OVF_MAX) ovf[o] = make_int4(r, col, __float_as_int(v), 0);
      }
    }
    return;
  }

  // ---- GEMM: weighted(bf16) = U @ W, 128 rows/block, 4 waves x 32 rows ----
  const int gb = blockIdx.x - nchunks;
  {
    // Build Wt[n][k] = bf16(W[k][n]) in LDS directly from W (L2-broadcast).
    const int k0 = (t >> 4) * 8;
    const int n0 = (t & 15) * 8;
    float v[8][8];
#pragma unroll
    for (int kk = 0; kk < 8; ++kk) {
      float4 a = *(const float4*)(W + (k0 + kk) * DD + n0);
      float4 b = *(const float4*)(W + (k0 + kk) * DD + n0 + 4);
      v[kk][0] = a.x; v[kk][1] = a.y; v[kk][2] = a.z; v[kk][3] = a.w;
      v[kk][4] = b.x; v[kk][5] = b.y; v[kk][6] = b.z; v[kk][7] = b.w;
    }
#pragma unroll
    for (int nn = 0; nn < 8; ++nn) {
      uint4 d;
      d.x = pack_bf16_2(v[0][nn], v[1][nn]);
      d.y = pack_bf16_2(v[2][nn], v[3][nn]);
      d.z = pack_bf16_2(v[4][nn], v[5][nn]);
      d.w = pack_bf16_2(v[6][nn], v[7][nn]);
      *(uint4*)(&sm.Wt[n0 + nn][k0]) = d;
    }
  }
  __syncthreads();

  const int blk_row0 = gb * 128;
  const int w = t >> 6;
  const int lane = t & 63;
  const int m = lane & 15;
  const int quad = lane >> 4;
  const int row_base = blk_row0 + w * 32;

  short8 afrag[2][4];
#pragma unroll
  for (int s = 0; s < 2; ++s) {
    const int r = min(row_base + s * 16 + m, N - 1);
    const float* up = U + (size_t)r * DD + quad * 8;
#pragma unroll
    for (int c = 0; c < 4; ++c) {
      float4 x = *(const float4*)(up + c * 32);
      float4 y = *(const float4*)(up + c * 32 + 4);
      union { unsigned u[4]; short8 v; } fr;
      fr.u[0] = pack_bf16_2(x.x, x.y);
      fr.u[1] = pack_bf16_2(x.z, x.w);
      fr.u[2] = pack_bf16_2(y.x, y.y);
      fr.u[3] = pack_bf16_2(y.z, y.w);
      afrag[s][c] = fr.v;
    }
  }

  f32x4 acc[2][8];
#pragma unroll
  for (int s = 0; s < 2; ++s)
#pragma unroll
    for (int ct = 0; ct < 8; ++ct) acc[s][ct] = (f32x4){0.f, 0.f, 0.f, 0.f};

#pragma unroll
  for (int c = 0; c < 4; ++c) {
#pragma unroll
    for (int ct = 0; ct < 8; ++ct) {
      short8 bfrag = *(const short8*)&sm.Wt[ct * 16 + m][c * 32 + quad * 8];
      acc[0][ct] = __builtin_amdgcn_mfma_f32_16x16x32_bf16(
          afrag[0][c], bfrag, acc[0][ct], 0, 0, 0);
      acc[1][ct] = __builtin_amdgcn_mfma_f32_16x16x32_bf16(
          afrag[1][c], bfrag, acc[1][ct], 0, 0, 0);
    }
  }

  // Epilogue: C/D layout col=lane&15, row=quad*4+reg  [measured m89/m91].
#pragma unroll
  for (int s = 0; s < 2; ++s) {
    const int rb = row_base + s * 16 + quad * 4;
#pragma unroll
    for (int ct = 0; ct < 8; ++ct) {
#pragma unroll
      for (int reg = 0; reg < 4; ++reg) {
        const int r = rb + reg;
        if (r < N) wb[(size_t)r * DD + ct * 16 + m] = f2bf(acc[s][ct][reg]);
      }
    }
  }
}

// ---------------------------------------------------------------------------
// Kernel B: one block per 64-row bucket. Counting-sort by row straight into
// slist (bucket region is block-private and L2-resident -> read it twice
// instead of staging in LDS; 12 KB LDS -> 8 blocks/CU, 32 waves/CU for
// gather latency hiding). Then per-row wide-gather accumulate: lane group
// g=lane>>4 owns an edge, slot sl=lane&15 owns 8 dims (16 B/lane).
// ---------------------------------------------------------------------------
__global__ __launch_bounds__(256) void kB_sort_accumulate(
    const int* __restrict__ binctr, const int2* __restrict__ bucket,
    const unsigned short* __restrict__ wb, const float* __restrict__ U,
    const int* __restrict__ ovf_cnt, const int4* __restrict__ ovf,
    float* __restrict__ out, int N) {
  __shared__ int2 slist[BC2];   // 11.3 KB row-sorted (col,val)
  __shared__ int scnt[64];
  __shared__ int sbase[64];
  __shared__ int scur[64];

  const int t = threadIdx.x;
  const int b = blockIdx.x;
  const int base = b << BSH;
  const int n = min(binctr[b], BC2);
  const int2* __restrict__ bkt = bucket + (size_t)b * BC2;

  if (t < 64) scnt[t] = 0;
  __syncthreads();

  // Pass 1: histogram by local row.
  for (int i = t; i < n; i += 256)
    atomicAdd(&scnt[(unsigned)bkt[i].x >> 22], 1);
  __syncthreads();

  if (t == 0) {
    int s = 0;
#pragma unroll 1
    for (int j = 0; j < 64; ++j) {
      sbase[j] = s;
      scur[j] = s;
      s += scnt[j];
    }
  }
  __syncthreads();

  // Pass 2: re-read (L2-hot) and place row-sorted.
  for (int i = t; i < n; i += 256) {
    const int2 e = bkt[i];
    const int pos = atomicAdd(&scur[(unsigned)e.x >> 22], 1);
    slist[pos] = make_int2(e.x & 0x3FFFFF, e.y);  // (col, val)
  }
  __syncthreads();

  const int lane = t & 63;
  const int w = t >> 6;
  const int g = lane >> 4;    // edge subgroup 0..3
  const int sl = lane & 15;   // dim slot: dims [8*sl .. 8*sl+7]
  const u16x8* __restrict__ WB8 = (const u16x8*)wb;  // row = 16 x u16x8
  const int nov = min(*ovf_cnt, OVF_MAX);  // wave-uniform broadcast load

  for (int rl = w; rl < 64; rl += 4) {
    const int r = base + rl;
    if (r >= N) break;
    const int cnt = scnt[rl];
    const int st = sbase[rl];

    float acc[8];
#pragma unroll
    for (int d = 0; d < 8; ++d) acc[d] = 0.f;

    int i = 0;
    // main: 16 edges / iter, 4 wide gathers in flight
    for (; i + 16 <= cnt; i += 16) {
      const int2 p0 = slist[st + i + g];
      const int2 p1 = slist[st + i + 4 + g];
      const int2 p2 = slist[st + i + 8 + g];
      const int2 p3 = slist[st + i + 12 + g];
      const u16x8 a0 = WB8[(size_t)p0.x * 16 + sl];
      const u16x8 a1 = WB8[(size_t)p1.x * 16 + sl];
      const u16x8 a2 = WB8[(size_t)p2.x * 16 + sl];
      const u16x8 a3 = WB8[(size_t)p3.x * 16 + sl];
      const float v0 = __int_as_float(p0.y);
      const float v1 = __int_as_float(p1.y);
      const float v2 = __int_as_float(p2.y);
      const float v3 = __int_as_float(p3.y);
#pragma unroll
      for (int d = 0; d < 8; ++d) {
        acc[d] = fmaf(v0, bf2f((unsigned short)a0[d]), acc[d]);
        acc[d] = fmaf(v1, bf2f((unsigned short)a1[d]), acc[d]);
        acc[d] = fmaf(v2, bf2f((unsigned short)a2[d]), acc[d]);
        acc[d] = fmaf(v3, bf2f((unsigned short)a3[d]), acc[d]);
      }
    }

    const int rem = cnt - i;  // 0..15
    if (rem > 8) {
      const int e0 = i + g, e1 = i + 4 + g, e2 = i + 8 + g, e3 = i + 12 + g;
      const int2 p0 = slist[st + min(e0, cnt - 1)];
      const int2 p1 = slist[st + min(e1, cnt - 1)];
      const int2 p2 = slist[st + min(e2, cnt - 1)];
      const int2 p3 = slist[st + min(e3, cnt - 1)];
      const u16x8 a0 = WB8[(size_t)p0.x * 16 + sl];
      const u16x8 a1 = WB8[(size_t)p1.x * 16 + sl];
      const u16x8 a2 = WB8[(size_t)p2.x * 16 + sl];
      const u16x8 a3 = WB8[(size_t)p3.x * 16 + sl];
      const float v0 = (e0 < cnt) ? __int_as_float(p0.y) : 0.f;
      const float v1 = (e1 < cnt) ? __int_as_float(p1.y) : 0.f;
      const float v2 = (e2 < cnt) ? __int_as_float(p2.y) : 0.f;
      const float v3 = (e3 < cnt) ? __int_as_float(p3.y) : 0.f;
#pragma unroll
      for (int d = 0; d < 8; ++d) {
        acc[d] = fmaf(v0, bf2f((unsigned short)a0[d]), acc[d]);
        acc[d] = fmaf(v1, bf2f((unsigned short)a1[d]), acc[d]);
        acc[d] = fmaf(v2, bf2f((unsigned short)a2[d]), acc[d]);
        acc[d] = fmaf(v3, bf2f((unsigned short)a3[d]), acc[d]);
      }
    } else if (rem > 0) {
      const int e0 = i + g, e1 = i + 4 + g;
      const int2 p0 = slist[st + min(e0, cnt - 1)];
      const int2 p1 = slist[st + min(e1, cnt - 1)];
      const u16x8 a0 = WB8[(size_t)p0.x * 16 + sl];
      const u16x8 a1 = WB8[(size_t)p1.x * 16 + sl];
      const float v0 = (e0 < cnt) ? __int_as_float(p0.y) : 0.f;
      const float v1 = (e1 < cnt) ? __int_as_float(p1.y) : 0.f;
#pragma unroll
      for (int d = 0; d < 8; ++d) {
        acc[d] = fmaf(v0, bf2f((unsigned short)a0[d]), acc[d]);
        acc[d] = fmaf(v1, bf2f((unsigned short)a1[d]), acc[d]);
      }
    }

    // reduce the 4 edge-subgroups: lanes {sl, sl+16, sl+32, sl+48} -> sl
#pragma unroll
    for (int d = 0; d < 8; ++d) {
      acc[d] += __shfl_xor(acc[d], 16, 64);
      acc[d] += __shfl_xor(acc[d], 32, 64);
    }

    // overflow entries (normally empty)
    if (nov > 0 && lane < 16) {
      for (int o = 0; o < nov; ++o) {
        const int4 e = ovf[o];
        if (e.x == r) {
          const float v = __int_as_float(e.z);
          const u16x8 a = WB8[(size_t)e.y * 16 + sl];
#pragma unroll
          for (int d = 0; d < 8; ++d)
            acc[d] = fmaf(v, bf2f((unsigned short)a[d]), acc[d]);
        }
      }
    }

    // residual add + store (quarter-wave covers the full 512 B row)
    if (lane < 16) {
      const float* up = U + (size_t)r * DD + sl * 8;
      const float4 u0 = *(const float4*)up;
      const float4 u1 = *(const float4*)(up + 4);
      float4 o0, o1;
      o0.x = acc[0] + u0.x; o0.y = acc[1] + u0.y;
      o0.z = acc[2] + u0.z; o0.w = acc[3] + u0.w;
      o1.x = acc[4] + u1.x; o1.y = acc[5] + u1.y;
      o1.z = acc[6] + u1.z; o1.w = acc[7] + u1.w;
      float* op = out + (size_t)r * DD + sl * 8;
      *(float4*)op = o0;
      *(float4*)(op + 4) = o1;
    }
  }
}

// ===========================================================================
// Fallback path (ws too small): transpose + gemm(copy residual) + atomics.
// ===========================================================================
__global__ __launch_bounds__(256) void p1_bucket(
    const float* __restrict__ W, unsigned short* __restrict__ Wtg,
    int E) {
  const int t = threadIdx.x;
  const int k0 = (t >> 4) * 8;
  const int n0 = (t & 15) * 8;
  float v[8][8];
#pragma unroll
  for (int kk = 0; kk < 8; ++kk) {
    float4 a = *(const float4*)(W + (k0 + kk) * DD + n0);
    float4 b = *(const float4*)(W + (k0 + kk) * DD + n0 + 4);
    v[kk][0] = a.x; v[kk][1] = a.y; v[kk][2] = a.z; v[kk][3] = a.w;
    v[kk][4] = b.x; v[kk][5] = b.y; v[kk][6] = b.z; v[kk][7] = b.w;
  }
#pragma unroll
  for (int nn = 0; nn < 8; ++nn) {
    uint4 d;
    d.x = pack_bf16_2(v[0][nn], v[1][nn]);
    d.y = pack_bf16_2(v[2][nn], v[3][nn]);
    d.z = pack_bf16_2(v[4][nn], v[5][nn]);
    d.w = pack_bf16_2(v[6][nn], v[7][nn]);
    *(uint4*)(Wtg + (size_t)(n0 + nn) * DD + k0) = d;
  }
}

__global__ __launch_bounds__(256) void k2_gemm_copy(
    const float* __restrict__ U, const unsigned short* __restrict__ Wtg,
    unsigned short* __restrict__ wb, float* __restrict__ out, int N) {
  __shared__ unsigned short Wt[DD][WTS];
  const int t = threadIdx.x;
  const int gb = blockIdx.x;
#pragma unroll
  for (int i = 0; i < 8; ++i) {
    const int s = t + 256 * i;
    const int nn = s >> 4;
    const int k0 = (s & 15) * 8;
    uint4 d = *(const uint4*)(Wtg + (size_t)nn * DD + k0);
    *(uint4*)(&Wt[nn][k0]) = d;
  }
  const int blk_row0 = gb * 128;
  {
    const int nrow = min(128, N - blk_row0);
    const float4* U4 = (const float4*)(U + (size_t)blk_row0 * DD);
    float4* O4 = (float4*)(out + (size_t)blk_row0 * DD);
    for (int i = t; i < nrow * 32; i += 256) O4[i] = U4[i];
  }
  __syncthreads();

  const int w = t >> 6;
  const int lane = t & 63;
  const int m = lane & 15;
  const int quad = lane >> 4;
  const int row_base = blk_row0 + w * 32;

  short8 afrag[2][4];
#pragma unroll
  for (int s = 0; s < 2; ++s) {
    const int r = min(row_base + s * 16 + m, N - 1);
    const float* up = U + (size_t)r * DD + quad * 8;
#pragma unroll
    for (int c = 0; c < 4; ++c) {
      float4 x = *(const float4*)(up + c * 32);
      float4 y = *(const float4*)(up + c * 32 + 4);
      union { unsigned u[4]; short8 v; } fr;
      fr.u[0] = pack_bf16_2(x.x, x.y);
      fr.u[1] = pack_bf16_2(x.z, x.w);
      fr.u[2] = pack_bf16_2(y.x, y.y);
      fr.u[3] = pack_bf16_2(y.z, y.w);
      afrag[s][c] = fr.v;
    }
  }

  f32x4 acc[2][8];
#pragma unroll
  for (int s = 0; s < 2; ++s)
#pragma unroll
    for (int ct = 0; ct < 8; ++ct) acc[s][ct] = (f32x4){0.f, 0.f, 0.f, 0.f};

#pragma unroll
  for (int c = 0; c < 4; ++c) {
#pragma unroll
    for (int ct = 0; ct < 8; ++ct) {
      short8 bfrag = *(const short8*)&Wt[ct * 16 + m][c * 32 + quad * 8];
      acc[0][ct] = __builtin_amdgcn_mfma_f32_16x16x32_bf16(
          afrag[0][c], bfrag, acc[0][ct], 0, 0, 0);
      acc[1][ct] = __builtin_amdgcn_mfma_f32_16x16x32_bf16(
          afrag[1][c], bfrag, acc[1][ct], 0, 0, 0);
    }
  }

#pragma unroll
  for (int s = 0; s < 2; ++s) {
    const int rb = row_base + s * 16 + quad * 4;
#pragma unroll
    for (int ct = 0; ct < 8; ++ct) {
#pragma unroll
      for (int reg = 0; reg < 4; ++reg) {
        const int r = rb + reg;
        if (r < N) wb[(size_t)r * DD + ct * 16 + m] = f2bf(acc[s][ct][reg]);
      }
    }
  }
}

__global__ __launch_bounds__(256) void scatter_kernel(
    const int* __restrict__ rows, const int* __restrict__ cols,
    const float* __restrict__ vals, const unsigned short* __restrict__ wb,
    float* __restrict__ out, int E) {
  const int tid = blockIdx.x * 256 + threadIdx.x;
  const int e = tid >> 6;
  if (e >= E) return;
  const int lane = tid & 63;

  const int row = rows[e];
  const int col = cols[e];
  const float v = vals[e];

  const ushort2 w = ((const ushort2*)wb)[(size_t)col * 64 + lane];
  float* dst = out + (size_t)row * DD + lane * 2;
  unsafeAtomicAdd(dst, v * bf2f(w.x));
  unsafeAtomicAdd(dst + 1, v * bf2f(w.y));
}

static inline size_t align_up(size_t x, size_t a) { return (x + a - 1) & ~(a - 1); }

extern "C" void kernel_launch(void* const* d_in, const int* in_sizes, int n_in,
                              void* d_out, int out_size, void* d_ws, size_t ws_size,
                              hipStream_t stream) {
  const float* U = (const float*)d_in[0];     // [N, 128]
  const float* W = (const float*)d_in[1];     // [128, 128]
  const int* rows = (const int*)d_in[2];      // [E]
  const int* cols = (const int*)d_in[3];      // [E]
  const float* vals = (const float*)d_in[4];  // [E]
  float* out = (float*)d_out;                 // [N, 128]

  const int N = in_sizes[0] / DD;
  const int E = in_sizes[2];
  const int gemmBlocks = (N + 127) / 128;
  const int nchunks = (E + EPB - 1) / EPB;       // 63 for E=800000
  const int nbkt = (N + (1 << BSH) - 1) >> BSH;  // 782 for N=50000

  // Workspace layout (16 B aligned segments)
  char* ws = (char*)d_ws;
  size_t off = 0;
  unsigned short* wb = (unsigned short*)(ws + off);
  off = align_up(off + (size_t)N * DD * sizeof(unsigned short), 16);
  unsigned short* Wtg = (unsigned short*)(ws + off);  // fallback only
  off = align_up(off + (size_t)DD * DD * sizeof(unsigned short), 16);
  int* binctr = (int*)(ws + off);  // NB2 bins + ovf counter, zeroed together
  int* ovf_cnt = binctr + NB2;
  off = align_up(off + (NB2 + 4) * sizeof(int), 16);
  int4* ovf = (int4*)(ws + off);
  off = align_up(off + (size_t)OVF_MAX * sizeof(int4), 16);
  int2* bucket = (int2*)(ws + off);
  off = align_up(off + (size_t)nbkt * BC2 * sizeof(int2), 16);
  const bool fast_ok = (off <= ws_size) && (nbkt <= NB2);

  if (fast_ok) {
    hipMemsetAsync(binctr, 0, (NB2 + 1) * sizeof(int), stream);  // 3.2 KB
    // A: bucket scatter (blocks [0,nchunks)) || GEMM (blocks [nchunks,..))
    kA_scatter_gemm<<<nchunks + gemmBlocks, 256, 0, stream>>>(
        U, W, rows, cols, vals, binctr, bucket, ovf_cnt, ovf, wb, N, E,
        nchunks, nbkt);
    // B: per-bucket LDS counting sort + wide-gather accumulate
    kB_sort_accumulate<<<nbkt, 256, 0, stream>>>(
        binctr, bucket, wb, U, ovf_cnt, ovf, out, N);
  } else {
    // Fallback: transpose, gemm w/ residual copy, atomic scatter.
    p1_bucket<<<1, 256, 0, stream>>>(W, Wtg, E);
    k2_gemm_copy<<<gemmBlocks, 256, 0, stream>>>(U, Wtg, wb, out, N);
    const long long total = (long long)E * 64;
    scatter_kernel<<<(int)((total + 255) / 256), 256, 0, stream>>>(
        rows, cols, vals, wb, out, E);
  }
}

// Round 5
// 148.639 us; speedup vs baseline: 1.1669x; 1.1669x over previous
//
#include <hip/hip_runtime.h>

#define DD 128         // EMBED_DIM
#define OVF_MAX 4096   // overflow list capacity (int4 entries)
#define EPB 2048       // edges per scatter chunk (392 chunks = parallelism)
#define BSH 6          // bucket = row >> 6 (64 rows/bucket)
#define NB2 800        // max buckets (ceil(50000/64)=782)
#define BC2 1408       // bucket capacity: lambda=1024, +12 sigma
#define WTS 136

typedef __attribute__((ext_vector_type(8))) short short8;           // 8 bf16
typedef __attribute__((ext_vector_type(8))) unsigned short u16x8;   // 8 bf16
typedef __attribute__((ext_vector_type(4))) float f32x4;            // MFMA C/D

static __device__ __forceinline__ unsigned pack_bf16_2(float lo, float hi) {
  return __builtin_amdgcn_perm(__float_as_uint(hi) + 0x8000u,
                               __float_as_uint(lo) + 0x8000u, 0x07060302u);
}
static __device__ __forceinline__ unsigned short f2bf(float f) {
  return (unsigned short)((__float_as_uint(f) + 0x8000u) >> 16);
}
static __device__ __forceinline__ float bf2f(unsigned short h) {
  return __uint_as_float((unsigned)h << 16);
}

// ---------------------------------------------------------------------------
// Kernel A: blocks [0,nchunks) bucket-scatter edges into 64-row buckets
// (EPB=2048 -> 392 scatter blocks: parallelism is the scatter's lever, NOT
// run length -- measured R3 vs R4: 63 big chunks = 72 us, 392 small = <45).
// Blocks [nchunks,..): MFMA GEMM with per-block W-transpose in LDS.
// ---------------------------------------------------------------------------
__global__ __launch_bounds__(256) void kA_scatter_gemm(
    const float* __restrict__ U, const float* __restrict__ W,
    const int* __restrict__ rows, const int* __restrict__ cols,
    const float* __restrict__ vals, int* __restrict__ binctr,
    int2* __restrict__ bucket, int* __restrict__ ovf_cnt,
    int4* __restrict__ ovf, unsigned short* __restrict__ wb,
    int N, int E, int nchunks, int nbkt) {
  __shared__ union {
    struct {
      int lrow[EPB];   // 8 KB staged rows
      int hist[NB2];   // 3.2 KB
      int gbase[NB2];
      int lcur[NB2];
    } p1;              // 17.6 KB
    unsigned short Wt[DD][WTS];  // 34.8 KB
  } sm;
  const int t = threadIdx.x;

  if ((int)blockIdx.x < nchunks) {
    // ---- bucket scatter for one 2048-edge chunk ----
    const int c0 = blockIdx.x * EPB;
    const int n = min(EPB, E - c0);

    for (int j = t; j < nbkt; j += 256) { sm.p1.hist[j] = 0; sm.p1.lcur[j] = 0; }
    __syncthreads();

    // Pass A: stage rows, histogram by bucket.
    for (int i = t; i < n; i += 256) {
      const int r = rows[c0 + i];
      sm.p1.lrow[i] = r;
      atomicAdd(&sm.p1.hist[r >> BSH], 1);
    }
    __syncthreads();

    // Reserve contiguous runs in each bucket.
    for (int j = t; j < nbkt; j += 256)
      if (sm.p1.hist[j] > 0)
        sm.p1.gbase[j] = atomicAdd(&binctr[j], sm.p1.hist[j]);
    __syncthreads();

    // Pass B: place edges into runs (cols/vals re-read coalesced, L2-hot).
    for (int i = t; i < n; i += 256) {
      const int r = sm.p1.lrow[i];
      const int b = r >> BSH;
      const int lpos = atomicAdd(&sm.p1.lcur[b], 1);
      const int idx = sm.p1.gbase[b] + lpos;
      const int col = cols[c0 + i];
      const float v = vals[c0 + i];
      if (idx < BC2) {
        // pack: bits[27:22] = row&63, bits[21:0] = col (col < 4M)
        bucket[(size_t)b * BC2 + idx] =
            make_int2(((r & 63) << 22) | col, __float_as_int(v));
      } else {
        const int o = atomicAdd(ovf_cnt, 1);
        if (o < OVF_MAX) ovf[o] = make_int4(r, col, __float_as_int(v), 0);
      }
    }
    return;
  }

  // ---- GEMM: weighted(bf16) = U @ W, 128 rows/block, 4 waves x 32 rows ----
  const int gb = blockIdx.x - nchunks;
  {
    // Build Wt[n][k] = bf16(W[k][n]) in LDS directly from W (L2-broadcast).
    const int k0 = (t >> 4) * 8;
    const int n0 = (t & 15) * 8;
    float v[8][8];
#pragma unroll
    for (int kk = 0; kk < 8; ++kk) {
      float4 a = *(const float4*)(W + (k0 + kk) * DD + n0);
      float4 b = *(const float4*)(W + (k0 + kk) * DD + n0 + 4);
      v[kk][0] = a.x; v[kk][1] = a.y; v[kk][2] = a.z; v[kk][3] = a.w;
      v[kk][4] = b.x; v[kk][5] = b.y; v[kk][6] = b.z; v[kk][7] = b.w;
    }
#pragma unroll
    for (int nn = 0; nn < 8; ++nn) {
      uint4 d;
      d.x = pack_bf16_2(v[0][nn], v[1][nn]);
      d.y = pack_bf16_2(v[2][nn], v[3][nn]);
      d.z = pack_bf16_2(v[4][nn], v[5][nn]);
      d.w = pack_bf16_2(v[6][nn], v[7][nn]);
      *(uint4*)(&sm.Wt[n0 + nn][k0]) = d;
    }
  }
  __syncthreads();

  const int blk_row0 = gb * 128;
  const int w = t >> 6;
  const int lane = t & 63;
  const int m = lane & 15;
  const int quad = lane >> 4;
  const int row_base = blk_row0 + w * 32;

  short8 afrag[2][4];
#pragma unroll
  for (int s = 0; s < 2; ++s) {
    const int r = min(row_base + s * 16 + m, N - 1);
    const float* up = U + (size_t)r * DD + quad * 8;
#pragma unroll
    for (int c = 0; c < 4; ++c) {
      float4 x = *(const float4*)(up + c * 32);
      float4 y = *(const float4*)(up + c * 32 + 4);
      union { unsigned u[4]; short8 v; } fr;
      fr.u[0] = pack_bf16_2(x.x, x.y);
      fr.u[1] = pack_bf16_2(x.z, x.w);
      fr.u[2] = pack_bf16_2(y.x, y.y);
      fr.u[3] = pack_bf16_2(y.z, y.w);
      afrag[s][c] = fr.v;
    }
  }

  f32x4 acc[2][8];
#pragma unroll
  for (int s = 0; s < 2; ++s)
#pragma unroll
    for (int ct = 0; ct < 8; ++ct) acc[s][ct] = (f32x4){0.f, 0.f, 0.f, 0.f};

#pragma unroll
  for (int c = 0; c < 4; ++c) {
#pragma unroll
    for (int ct = 0; ct < 8; ++ct) {
      short8 bfrag = *(const short8*)&sm.Wt[ct * 16 + m][c * 32 + quad * 8];
      acc[0][ct] = __builtin_amdgcn_mfma_f32_16x16x32_bf16(
          afrag[0][c], bfrag, acc[0][ct], 0, 0, 0);
      acc[1][ct] = __builtin_amdgcn_mfma_f32_16x16x32_bf16(
          afrag[1][c], bfrag, acc[1][ct], 0, 0, 0);
    }
  }

  // Epilogue: C/D layout col=lane&15, row=quad*4+reg  [measured m89/m91].
#pragma unroll
  for (int s = 0; s < 2; ++s) {
    const int rb = row_base + s * 16 + quad * 4;
#pragma unroll
    for (int ct = 0; ct < 8; ++ct) {
#pragma unroll
      for (int reg = 0; reg < 4; ++reg) {
        const int r = rb + reg;
        if (r < N) wb[(size_t)r * DD + ct * 16 + m] = f2bf(acc[s][ct][reg]);
      }
    }
  }
}

// ---------------------------------------------------------------------------
// Kernel B: one block per 64-row bucket. Counting-sort by row straight into
// slist (bucket region is block-private and L2-resident -> read it twice
// instead of staging in LDS; 12 KB LDS -> 8 blocks/CU, 32 waves/CU for
// gather latency hiding). Then per-row wide-gather accumulate: lane group
// g=lane>>4 owns an edge, slot sl=lane&15 owns 8 dims (16 B/lane).
// ---------------------------------------------------------------------------
__global__ __launch_bounds__(256) void kB_sort_accumulate(
    const int* __restrict__ binctr, const int2* __restrict__ bucket,
    const unsigned short* __restrict__ wb, const float* __restrict__ U,
    const int* __restrict__ ovf_cnt, const int4* __restrict__ ovf,
    float* __restrict__ out, int N) {
  __shared__ int2 slist[BC2];   // 11.3 KB row-sorted (col,val)
  __shared__ int scnt[64];
  __shared__ int sbase[64];
  __shared__ int scur[64];

  const int t = threadIdx.x;
  const int b = blockIdx.x;
  const int base = b << BSH;
  const int n = min(binctr[b], BC2);
  const int2* __restrict__ bkt = bucket + (size_t)b * BC2;

  if (t < 64) scnt[t] = 0;
  __syncthreads();

  // Pass 1: histogram by local row.
  for (int i = t; i < n; i += 256)
    atomicAdd(&scnt[(unsigned)bkt[i].x >> 22], 1);
  __syncthreads();

  if (t == 0) {
    int s = 0;
#pragma unroll 1
    for (int j = 0; j < 64; ++j) {
      sbase[j] = s;
      scur[j] = s;
      s += scnt[j];
    }
  }
  __syncthreads();

  // Pass 2: re-read (L2-hot) and place row-sorted.
  for (int i = t; i < n; i += 256) {
    const int2 e = bkt[i];
    const int pos = atomicAdd(&scur[(unsigned)e.x >> 22], 1);
    slist[pos] = make_int2(e.x & 0x3FFFFF, e.y);  // (col, val)
  }
  __syncthreads();

  const int lane = t & 63;
  const int w = t >> 6;
  const int g = lane >> 4;    // edge subgroup 0..3
  const int sl = lane & 15;   // dim slot: dims [8*sl .. 8*sl+7]
  const u16x8* __restrict__ WB8 = (const u16x8*)wb;  // row = 16 x u16x8
  const int nov = min(*ovf_cnt, OVF_MAX);  // wave-uniform broadcast load

  for (int rl = w; rl < 64; rl += 4) {
    const int r = base + rl;
    if (r >= N) break;
    const int cnt = scnt[rl];
    const int st = sbase[rl];

    float acc[8];
#pragma unroll
    for (int d = 0; d < 8; ++d) acc[d] = 0.f;

    int i = 0;
    // main: 16 edges / iter, 4 wide gathers in flight
    for (; i + 16 <= cnt; i += 16) {
      const int2 p0 = slist[st + i + g];
      const int2 p1 = slist[st + i + 4 + g];
      const int2 p2 = slist[st + i + 8 + g];
      const int2 p3 = slist[st + i + 12 + g];
      const u16x8 a0 = WB8[(size_t)p0.x * 16 + sl];
      const u16x8 a1 = WB8[(size_t)p1.x * 16 + sl];
      const u16x8 a2 = WB8[(size_t)p2.x * 16 + sl];
      const u16x8 a3 = WB8[(size_t)p3.x * 16 + sl];
      const float v0 = __int_as_float(p0.y);
      const float v1 = __int_as_float(p1.y);
      const float v2 = __int_as_float(p2.y);
      const float v3 = __int_as_float(p3.y);
#pragma unroll
      for (int d = 0; d < 8; ++d) {
        acc[d] = fmaf(v0, bf2f((unsigned short)a0[d]), acc[d]);
        acc[d] = fmaf(v1, bf2f((unsigned short)a1[d]), acc[d]);
        acc[d] = fmaf(v2, bf2f((unsigned short)a2[d]), acc[d]);
        acc[d] = fmaf(v3, bf2f((unsigned short)a3[d]), acc[d]);
      }
    }

    const int rem = cnt - i;  // 0..15
    if (rem > 8) {
      const int e0 = i + g, e1 = i + 4 + g, e2 = i + 8 + g, e3 = i + 12 + g;
      const int2 p0 = slist[st + min(e0, cnt - 1)];
      const int2 p1 = slist[st + min(e1, cnt - 1)];
      const int2 p2 = slist[st + min(e2, cnt - 1)];
      const int2 p3 = slist[st + min(e3, cnt - 1)];
      const u16x8 a0 = WB8[(size_t)p0.x * 16 + sl];
      const u16x8 a1 = WB8[(size_t)p1.x * 16 + sl];
      const u16x8 a2 = WB8[(size_t)p2.x * 16 + sl];
      const u16x8 a3 = WB8[(size_t)p3.x * 16 + sl];
      const float v0 = (e0 < cnt) ? __int_as_float(p0.y) : 0.f;
      const float v1 = (e1 < cnt) ? __int_as_float(p1.y) : 0.f;
      const float v2 = (e2 < cnt) ? __int_as_float(p2.y) : 0.f;
      const float v3 = (e3 < cnt) ? __int_as_float(p3.y) : 0.f;
#pragma unroll
      for (int d = 0; d < 8; ++d) {
        acc[d] = fmaf(v0, bf2f((unsigned short)a0[d]), acc[d]);
        acc[d] = fmaf(v1, bf2f((unsigned short)a1[d]), acc[d]);
        acc[d] = fmaf(v2, bf2f((unsigned short)a2[d]), acc[d]);
        acc[d] = fmaf(v3, bf2f((unsigned short)a3[d]), acc[d]);
      }
    } else if (rem > 0) {
      const int e0 = i + g, e1 = i + 4 + g;
      const int2 p0 = slist[st + min(e0, cnt - 1)];
      const int2 p1 = slist[st + min(e1, cnt - 1)];
      const u16x8 a0 = WB8[(size_t)p0.x * 16 + sl];
      const u16x8 a1 = WB8[(size_t)p1.x * 16 + sl];
      const float v0 = (e0 < cnt) ? __int_as_float(p0.y) : 0.f;
      const float v1 = (e1 < cnt) ? __int_as_float(p1.y) : 0.f;
#pragma unroll
      for (int d = 0; d < 8; ++d) {
        acc[d] = fmaf(v0, bf2f((unsigned short)a0[d]), acc[d]);
        acc[d] = fmaf(v1, bf2f((unsigned short)a1[d]), acc[d]);
      }
    }

    // reduce the 4 edge-subgroups: lanes {sl, sl+16, sl+32, sl+48} -> sl
#pragma unroll
    for (int d = 0; d < 8; ++d) {
      acc[d] += __shfl_xor(acc[d], 16, 64);
      acc[d] += __shfl_xor(acc[d], 32, 64);
    }

    // overflow entries (normally empty)
    if (nov > 0 && lane < 16) {
      for (int o = 0; o < nov; ++o) {
        const int4 e = ovf[o];
        if (e.x == r) {
          const float v = __int_as_float(e.z);
          const u16x8 a = WB8[(size_t)e.y * 16 + sl];
#pragma unroll
          for (int d = 0; d < 8; ++d)
            acc[d] = fmaf(v, bf2f((unsigned short)a[d]), acc[d]);
        }
      }
    }

    // residual add + store (quarter-wave covers the full 512 B row)
    if (lane < 16) {
      const float* up = U + (size_t)r * DD + sl * 8;
      const float4 u0 = *(const float4*)up;
      const float4 u1 = *(const float4*)(up + 4);
      float4 o0, o1;
      o0.x = acc[0] + u0.x; o0.y = acc[1] + u0.y;
      o0.z = acc[2] + u0.z; o0.w = acc[3] + u0.w;
      o1.x = acc[4] + u1.x; o1.y = acc[5] + u1.y;
      o1.z = acc[6] + u1.z; o1.w = acc[7] + u1.w;
      float* op = out + (size_t)r * DD + sl * 8;
      *(float4*)op = o0;
      *(float4*)(op + 4) = o1;
    }
  }
}

// ===========================================================================
// Fallback path (ws too small): transpose + gemm(copy residual) + atomics.
// ===========================================================================
__global__ __launch_bounds__(256) void p1_bucket(
    const float* __restrict__ W, unsigned short* __restrict__ Wtg,
    int E) {
  const int t = threadIdx.x;
  const int k0 = (t >> 4) * 8;
  const int n0 = (t & 15) * 8;
  float v[8][8];
#pragma unroll
  for (int kk = 0; kk < 8; ++kk) {
    float4 a = *(const float4*)(W + (k0 + kk) * DD + n0);
    float4 b = *(const float4*)(W + (k0 + kk) * DD + n0 + 4);
    v[kk][0] = a.x; v[kk][1] = a.y; v[kk][2] = a.z; v[kk][3] = a.w;
    v[kk][4] = b.x; v[kk][5] = b.y; v[kk][6] = b.z; v[kk][7] = b.w;
  }
#pragma unroll
  for (int nn = 0; nn < 8; ++nn) {
    uint4 d;
    d.x = pack_bf16_2(v[0][nn], v[1][nn]);
    d.y = pack_bf16_2(v[2][nn], v[3][nn]);
    d.z = pack_bf16_2(v[4][nn], v[5][nn]);
    d.w = pack_bf16_2(v[6][nn], v[7][nn]);
    *(uint4*)(Wtg + (size_t)(n0 + nn) * DD + k0) = d;
  }
}

__global__ __launch_bounds__(256) void k2_gemm_copy(
    const float* __restrict__ U, const unsigned short* __restrict__ Wtg,
    unsigned short* __restrict__ wb, float* __restrict__ out, int N) {
  __shared__ unsigned short Wt[DD][WTS];
  const int t = threadIdx.x;
  const int gb = blockIdx.x;
#pragma unroll
  for (int i = 0; i < 8; ++i) {
    const int s = t + 256 * i;
    const int nn = s >> 4;
    const int k0 = (s & 15) * 8;
    uint4 d = *(const uint4*)(Wtg + (size_t)nn * DD + k0);
    *(uint4*)(&Wt[nn][k0]) = d;
  }
  const int blk_row0 = gb * 128;
  {
    const int nrow = min(128, N - blk_row0);
    const float4* U4 = (const float4*)(U + (size_t)blk_row0 * DD);
    float4* O4 = (float4*)(out + (size_t)blk_row0 * DD);
    for (int i = t; i < nrow * 32; i += 256) O4[i] = U4[i];
  }
  __syncthreads();

  const int w = t >> 6;
  const int lane = t & 63;
  const int m = lane & 15;
  const int quad = lane >> 4;
  const int row_base = blk_row0 + w * 32;

  short8 afrag[2][4];
#pragma unroll
  for (int s = 0; s < 2; ++s) {
    const int r = min(row_base + s * 16 + m, N - 1);
    const float* up = U + (size_t)r * DD + quad * 8;
#pragma unroll
    for (int c = 0; c < 4; ++c) {
      float4 x = *(const float4*)(up + c * 32);
      float4 y = *(const float4*)(up + c * 32 + 4);
      union { unsigned u[4]; short8 v; } fr;
      fr.u[0] = pack_bf16_2(x.x, x.y);
      fr.u[1] = pack_bf16_2(x.z, x.w);
      fr.u[2] = pack_bf16_2(y.x, y.y);
      fr.u[3] = pack_bf16_2(y.z, y.w);
      afrag[s][c] = fr.v;
    }
  }

  f32x4 acc[2][8];
#pragma unroll
  for (int s = 0; s < 2; ++s)
#pragma unroll
    for (int ct = 0; ct < 8; ++ct) acc[s][ct] = (f32x4){0.f, 0.f, 0.f, 0.f};

#pragma unroll
  for (int c = 0; c < 4; ++c) {
#pragma unroll
    for (int ct = 0; ct < 8; ++ct) {
      short8 bfrag = *(const short8*)&Wt[ct * 16 + m][c * 32 + quad * 8];
      acc[0][ct] = __builtin_amdgcn_mfma_f32_16x16x32_bf16(
          afrag[0][c], bfrag, acc[0][ct], 0, 0, 0);
      acc[1][ct] = __builtin_amdgcn_mfma_f32_16x16x32_bf16(
          afrag[1][c], bfrag, acc[1][ct], 0, 0, 0);
    }
  }

#pragma unroll
  for (int s = 0; s < 2; ++s) {
    const int rb = row_base + s * 16 + quad * 4;
#pragma unroll
    for (int ct = 0; ct < 8; ++ct) {
#pragma unroll
      for (int reg = 0; reg < 4; ++reg) {
        const int r = rb + reg;
        if (r < N) wb[(size_t)r * DD + ct * 16 + m] = f2bf(acc[s][ct][reg]);
      }
    }
  }
}

__global__ __launch_bounds__(256) void scatter_kernel(
    const int* __restrict__ rows, const int* __restrict__ cols,
    const float* __restrict__ vals, const unsigned short* __restrict__ wb,
    float* __restrict__ out, int E) {
  const int tid = blockIdx.x * 256 + threadIdx.x;
  const int e = tid >> 6;
  if (e >= E) return;
  const int lane = tid & 63;

  const int row = rows[e];
  const int col = cols[e];
  const float v = vals[e];

  const ushort2 w = ((const ushort2*)wb)[(size_t)col * 64 + lane];
  float* dst = out + (size_t)row * DD + lane * 2;
  unsafeAtomicAdd(dst, v * bf2f(w.x));
  unsafeAtomicAdd(dst + 1, v * bf2f(w.y));
}

static inline size_t align_up(size_t x, size_t a) { return (x + a - 1) & ~(a - 1); }

extern "C" void kernel_launch(void* const* d_in, const int* in_sizes, int n_in,
                              void* d_out, int out_size, void* d_ws, size_t ws_size,
                              hipStream_t stream) {
  const float* U = (const float*)d_in[0];     // [N, 128]
  const float* W = (const float*)d_in[1];     // [128, 128]
  const int* rows = (const int*)d_in[2];      // [E]
  const int* cols = (const int*)d_in[3];      // [E]
  const float* vals = (const float*)d_in[4];  // [E]
  float* out = (float*)d_out;                 // [N, 128]

  const int N = in_sizes[0] / DD;
  const int E = in_sizes[2];
  const int gemmBlocks = (N + 127) / 128;
  const int nchunks = (E + EPB - 1) / EPB;       // 391 for E=800000
  const int nbkt = (N + (1 << BSH) - 1) >> BSH;  // 782 for N=50000

  // Workspace layout (16 B aligned segments)
  char* ws = (char*)d_ws;
  size_t off = 0;
  unsigned short* wb = (unsigned short*)(ws + off);
  off = align_up(off + (size_t)N * DD * sizeof(unsigned short), 16);
  unsigned short* Wtg = (unsigned short*)(ws + off);  // fallback only
  off = align_up(off + (size_t)DD * DD * sizeof(unsigned short), 16);
  int* binctr = (int*)(ws + off);  // NB2 bins + ovf counter, zeroed together
  int* ovf_cnt = binctr + NB2;
  off = align_up(off + (NB2 + 4) * sizeof(int), 16);
  int4* ovf = (int4*)(ws + off);
  off = align_up(off + (size_t)OVF_MAX * sizeof(int4), 16);
  int2* bucket = (int2*)(ws + off);
  off = align_up(off + (size_t)nbkt * BC2 * sizeof(int2), 16);
  const bool fast_ok = (off <= ws_size) && (nbkt <= NB2);

  if (fast_ok) {
    hipMemsetAsync(binctr, 0, (NB2 + 1) * sizeof(int), stream);  // 3.2 KB
    // A: bucket scatter (blocks [0,nchunks)) || GEMM (blocks [nchunks,..))
    kA_scatter_gemm<<<nchunks + gemmBlocks, 256, 0, stream>>>(
        U, W, rows, cols, vals, binctr, bucket, ovf_cnt, ovf, wb, N, E,
        nchunks, nbkt);
    // B: per-bucket LDS counting sort + wide-gather accumulate
    kB_sort_accumulate<<<nbkt, 256, 0, stream>>>(
        binctr, bucket, wb, U, ovf_cnt, ovf, out, N);
  } else {
    // Fallback: transpose, gemm w/ residual copy, atomic scatter.
    p1_bucket<<<1, 256, 0, stream>>>(W, Wtg, E);
    k2_gemm_copy<<<gemmBlocks, 256, 0, stream>>>(U, Wtg, wb, out, N);
    const long long total = (long long)E * 64;
    scatter_kernel<<<(int)((total + 255) / 256), 256, 0, stream>>>(
        rows, cols, vals, wb, out, E);
  }
}